// Round 7
// baseline (3374.710 us; speedup 1.0000x reference)
//
#include <hip/hip_runtime.h>

#define N_PTS 1000000
#define H_DIM 200
#define W_DIM 70400
#define FILL_V -9999999.0f

// ---------------------------------------------------------------------------
// Kernel A: per-pair MLP (4->18->36->36->1), 2 points per thread.
// Weights staged in LDS (rows padded to 16B -> ds_read_b128 broadcast).
// Each weight read feeds 8 FMAs across 2 independent chains; per-point LDS
// issue halves. __launch_bounds__(256,2) -> 256-VGPR budget, no AGPR spill.
// List entry: .x = value bits, .y = (point_index << 8) | row  (row<200<256).
// Last-write-wins scatter: point survives iff no LATER point hit (row,col).
// ---------------------------------------------------------------------------
__global__ void __launch_bounds__(256, 2) mlp_scatter_kernel(
    const float* __restrict__ input,        // [4][N]
    const int* __restrict__ tindex,         // [N][2] int32 (row, col)
    const float* __restrict__ w1, const float* __restrict__ b1,
    const float* __restrict__ w2, const float* __restrict__ b2,
    const float* __restrict__ w3, const float* __restrict__ b3,
    const float* __restrict__ w4, const float* __restrict__ b4,
    int* __restrict__ counts,               // [W]
    uint2* __restrict__ list,               // [W][maxk]
    int maxk)
{
    __shared__ float4 sw1[18];       // layer1: 18 rows of 4
    __shared__ float4 sw2[36 * 5];   // layer2: 36 rows, 18 padded to 20
    __shared__ float4 sw3[36 * 9];   // layer3: 36 rows of 36
    __shared__ float4 sw4[9];        // layer4: 1 row of 36
    __shared__ float  sb1[18], sb2[36], sb3[36];
    __shared__ float  sb4;

    const int t = threadIdx.x;
    {
        float* p = (float*)sw1;
        for (int k = t; k < 72; k += 256) p[k] = w1[k];
        p = (float*)sw2;
        for (int k = t; k < 720; k += 256) {
            int r = k / 20, c = k % 20;
            p[k] = (c < 18) ? w2[r * 18 + c] : 0.0f;
        }
        p = (float*)sw3;
        for (int k = t; k < 1296; k += 256) p[k] = w3[k];
        p = (float*)sw4;
        for (int k = t; k < 36; k += 256) p[k] = w4[k];
        for (int k = t; k < 18; k += 256) sb1[k] = b1[k];
        for (int k = t; k < 36; k += 256) sb2[k] = b2[k];
        for (int k = t; k < 36; k += 256) sb3[k] = b3[k];
        if (t == 0) sb4 = b4[0];
    }
    __syncthreads();

    // empty-branch (reference: tensor_index[0,0] == -1 -> no scatter)
    if (tindex[0] == -1) return;

    const int pr = blockIdx.x * 256 + t;    // pair index: points 2*pr, 2*pr+1
    if (2 * pr >= N_PTS) return;

    const float2 c0 = ((const float2*)(input            ))[pr];
    const float2 c1 = ((const float2*)(input +     N_PTS))[pr];
    const float2 c2 = ((const float2*)(input + 2 * N_PTS))[pr];
    const float2 c3 = ((const float2*)(input + 3 * N_PTS))[pr];

    float h1[2][20];
#pragma unroll
    for (int o = 0; o < 18; ++o) {
        const float4 wv = sw1[o];
        const float  bb = sb1[o];
        h1[0][o] = fmaxf(fmaf(wv.x, c0.x, fmaf(wv.y, c1.x,
                         fmaf(wv.z, c2.x, fmaf(wv.w, c3.x, bb)))), 0.0f);
        h1[1][o] = fmaxf(fmaf(wv.x, c0.y, fmaf(wv.y, c1.y,
                         fmaf(wv.z, c2.y, fmaf(wv.w, c3.y, bb)))), 0.0f);
    }
    h1[0][18] = h1[0][19] = 0.0f;
    h1[1][18] = h1[1][19] = 0.0f;

    float h2[2][36];
#pragma unroll
    for (int o = 0; o < 36; ++o) {
        float a0 = sb2[o], a1 = a0;
#pragma unroll
        for (int q = 0; q < 5; ++q) {
            const float4 wv = sw2[o * 5 + q];
            a0 = fmaf(wv.x, h1[0][q*4+0], a0); a0 = fmaf(wv.y, h1[0][q*4+1], a0);
            a0 = fmaf(wv.z, h1[0][q*4+2], a0); a0 = fmaf(wv.w, h1[0][q*4+3], a0);
            a1 = fmaf(wv.x, h1[1][q*4+0], a1); a1 = fmaf(wv.y, h1[1][q*4+1], a1);
            a1 = fmaf(wv.z, h1[1][q*4+2], a1); a1 = fmaf(wv.w, h1[1][q*4+3], a1);
        }
        h2[0][o] = fmaxf(a0, 0.0f);
        h2[1][o] = fmaxf(a1, 0.0f);
    }

    float h3[2][36];
#pragma unroll
    for (int o = 0; o < 36; ++o) {
        float a0 = sb3[o], a1 = a0;
#pragma unroll
        for (int q = 0; q < 9; ++q) {
            const float4 wv = sw3[o * 9 + q];
            a0 = fmaf(wv.x, h2[0][q*4+0], a0); a0 = fmaf(wv.y, h2[0][q*4+1], a0);
            a0 = fmaf(wv.z, h2[0][q*4+2], a0); a0 = fmaf(wv.w, h2[0][q*4+3], a0);
            a1 = fmaf(wv.x, h2[1][q*4+0], a1); a1 = fmaf(wv.y, h2[1][q*4+1], a1);
            a1 = fmaf(wv.z, h2[1][q*4+2], a1); a1 = fmaf(wv.w, h2[1][q*4+3], a1);
        }
        h3[0][o] = fmaxf(a0, 0.0f);
        h3[1][o] = fmaxf(a1, 0.0f);
    }

    float v0 = sb4, v1 = sb4;
#pragma unroll
    for (int q = 0; q < 9; ++q) {
        const float4 wv = sw4[q];
        v0 = fmaf(wv.x, h3[0][q*4+0], v0); v0 = fmaf(wv.y, h3[0][q*4+1], v0);
        v0 = fmaf(wv.z, h3[0][q*4+2], v0); v0 = fmaf(wv.w, h3[0][q*4+3], v0);
        v1 = fmaf(wv.x, h3[1][q*4+0], v1); v1 = fmaf(wv.y, h3[1][q*4+1], v1);
        v1 = fmaf(wv.z, h3[1][q*4+2], v1); v1 = fmaf(wv.w, h3[1][q*4+3], v1);
    }

    const int4 hw = ((const int4*)tindex)[pr];   // (h0,w0,h1,w1)
    {
        int pos = atomicAdd(&counts[hw.y], 1);
        if (pos < maxk)
            list[(size_t)hw.y * maxk + pos] =
                make_uint2(__float_as_uint(v0),
                           ((unsigned)(2 * pr) << 8) | (unsigned)hw.x);
    }
    {
        int pos = atomicAdd(&counts[hw.w], 1);
        if (pos < maxk)
            list[(size_t)hw.w * maxk + pos] =
                make_uint2(__float_as_uint(v1),
                           ((unsigned)(2 * pr + 1) << 8) | (unsigned)hw.z);
    }
}

// ---------------------------------------------------------------------------
// Kernel B: block (64,4) = 4 waves, one column per wave. Lane a holds slot a.
// Dedup via 64-bit per-wave winner table: atomicMax(tbl64[row],
// (key<<32)|value_bits). High word = (i<<8)|row orders by point index; low
// word carries the winning value. After __syncthreads(), each lane reads its
// row's winner VALUE; duplicate reads of the same winner are harmless under
// max. R4/R5 BUG was HERE: init covered rows 0..191 only ("lane+128 with
// lane<72" needs 72 lanes; wave has 64) -> rows 192..199 held garbage.
// 200 rows / 64 lanes = 4 strided passes: lane, +64, +128, +192(lane<8).
// ---------------------------------------------------------------------------
__global__ void __launch_bounds__(256) colmax_kernel(
    const int* __restrict__ tindex,
    const int* __restrict__ counts,
    const uint2* __restrict__ list,
    float* __restrict__ out,
    int maxk)
{
    __shared__ unsigned long long rowwin[4][200];
    const int lane = threadIdx.x;        // 0..63
    const int y    = threadIdx.y;        // 0..3
    const int w    = blockIdx.x * 4 + y; // column id, always < W_DIM (70400=4*17600)

    const bool empty = (tindex[0] == -1);

    if (blockIdx.x == 0 && lane == 0 && y == 0)
        out[W_DIM] = empty ? 0.0f : 1.0f;    // flag output

    int c = 0;
    if (!empty) {
        c = counts[w];
        if (c > maxk) c = maxk;
    }

    unsigned long long* tbl = rowwin[y];
    tbl[lane]       = 0ull;                  // rows   0.. 63
    tbl[lane + 64]  = 0ull;                  // rows  64..127
    tbl[lane + 128 - (lane >= 8 ? 0 : 0)] = 0ull;  // rows 128..191
    if (lane < 8) tbl[lane + 192] = 0ull;    // rows 192..199  (the R4/R5 fix)
    __syncthreads();

    uint2 e = make_uint2(0u, 0u);
    const bool have = (lane < c);
    if (have) {
        e = list[(size_t)w * maxk + lane];
        // key64: high = (i<<8)|row (orders by i within a row), low = value bits.
        const unsigned long long key64 =
            ((unsigned long long)e.y << 32) | (unsigned long long)e.x;
        atomicMax(&tbl[e.y & 0xFFu], key64);
    }
    __syncthreads();

    float v = FILL_V;
    if (have) {
        const unsigned long long winner = tbl[e.y & 0xFFu];
        v = __uint_as_float((unsigned)(winner & 0xFFFFFFFFull));
    }
#pragma unroll
    for (int off = 32; off > 0; off >>= 1)
        v = fmaxf(v, __shfl_down(v, off, 64));

    if (lane == 0) out[w] = v;
}

extern "C" void kernel_launch(void* const* d_in, const int* in_sizes, int n_in,
                              void* d_out, int out_size, void* d_ws, size_t ws_size,
                              hipStream_t stream) {
    const float* input  = (const float*)d_in[0];
    const int*   tindex = (const int*)d_in[1];   // int32 on device
    const float* w1 = (const float*)d_in[2];
    const float* b1 = (const float*)d_in[3];
    const float* w2 = (const float*)d_in[4];
    const float* b2 = (const float*)d_in[5];
    const float* w3 = (const float*)d_in[6];
    const float* b3 = (const float*)d_in[7];
    const float* w4 = (const float*)d_in[8];
    const float* b4 = (const float*)d_in[9];
    float* out = (float*)d_out;

    // workspace: counts [70400 int] | list [70400][maxk] uint2
    int*   counts = (int*)d_ws;
    uint2* list   = (uint2*)((char*)d_ws + (size_t)W_DIM * sizeof(int));

    size_t avail = (ws_size > (size_t)W_DIM * sizeof(int))
                       ? ws_size - (size_t)W_DIM * sizeof(int) : 0;
    int maxk = (int)(avail / ((size_t)W_DIM * sizeof(uint2)));
    if (maxk > 64) maxk = 64;
    if (maxk < 1)  maxk = 1;

    hipMemsetAsync(counts, 0, (size_t)W_DIM * sizeof(int), stream);

    // 2 points per thread -> 500k pair-threads
    const int pairs = N_PTS / 2;
    mlp_scatter_kernel<<<(pairs + 255) / 256, 256, 0, stream>>>(
        input, tindex, w1, b1, w2, b2, w3, b3, w4, b4, counts, list, maxk);

    // one wave per column, 4 waves per block; 70400/4 = 17600 exact blocks
    colmax_kernel<<<W_DIM / 4, dim3(64, 4), 0, stream>>>(
        tindex, counts, list, out, maxk);
}

// Round 8
// 199.246 us; speedup vs baseline: 16.9374x; 16.9374x over previous
//
#include <hip/hip_runtime.h>

#define N_PTS 1000000
#define H_DIM 200
#define W_DIM 70400
#define FILL_V -9999999.0f

// ---------------------------------------------------------------------------
// Kernel A: per-point MLP (4->18->36->36->1), ONE point per thread.
// Weights staged in LDS, rows padded to 16B -> ds_read_b128 broadcast
// (uniform address, conflict-free). Live set ~92 floats (peak: h2[36]+h3[36]).
// __launch_bounds__(256,2) -> 256-VGPR budget: fits in ARCH VGPRs.
// History: (256,4)/default gave 48/72 arch VGPRs + AGPR spill shuffling
// (~2x VALU, 106us); 2-pt/thread variant spilled to SCRATCH (9 GB HBM
// traffic, 3.3ms). 1-pt + 256-budget is the sweet spot.
// List entry: .x = value bits, .y = (point_index << 8) | row  (row<200<256).
// Last-write-wins scatter: point survives iff no LATER point hit (row,col).
// ---------------------------------------------------------------------------
__global__ void __launch_bounds__(256, 2) mlp_scatter_kernel(
    const float* __restrict__ input,        // [4][N]
    const int* __restrict__ tindex,         // [N][2] int32 (row, col)
    const float* __restrict__ w1, const float* __restrict__ b1,
    const float* __restrict__ w2, const float* __restrict__ b2,
    const float* __restrict__ w3, const float* __restrict__ b3,
    const float* __restrict__ w4, const float* __restrict__ b4,
    int* __restrict__ counts,               // [W]
    uint2* __restrict__ list,               // [W][maxk]
    int maxk)
{
    __shared__ float4 sw1[18];       // layer1: 18 rows of 4
    __shared__ float4 sw2[36 * 5];   // layer2: 36 rows, 18 padded to 20
    __shared__ float4 sw3[36 * 9];   // layer3: 36 rows of 36
    __shared__ float4 sw4[9];        // layer4: 1 row of 36
    __shared__ float  sb1[18], sb2[36], sb3[36];
    __shared__ float  sb4;

    const int t = threadIdx.x;
    {
        float* p = (float*)sw1;
        for (int k = t; k < 72; k += 256) p[k] = w1[k];
        p = (float*)sw2;
        for (int k = t; k < 720; k += 256) {
            int r = k / 20, c = k % 20;
            p[k] = (c < 18) ? w2[r * 18 + c] : 0.0f;
        }
        p = (float*)sw3;
        for (int k = t; k < 1296; k += 256) p[k] = w3[k];
        p = (float*)sw4;
        for (int k = t; k < 36; k += 256) p[k] = w4[k];
        for (int k = t; k < 18; k += 256) sb1[k] = b1[k];
        for (int k = t; k < 36; k += 256) sb2[k] = b2[k];
        for (int k = t; k < 36; k += 256) sb3[k] = b3[k];
        if (t == 0) sb4 = b4[0];
    }
    __syncthreads();

    // empty-branch (reference: tensor_index[0,0] == -1 -> no scatter)
    if (tindex[0] == -1) return;

    const int i = blockIdx.x * 256 + t;
    if (i >= N_PTS) return;

    const float x0 = input[0 * N_PTS + i];
    const float x1 = input[1 * N_PTS + i];
    const float x2 = input[2 * N_PTS + i];
    const float x3 = input[3 * N_PTS + i];

    float h1[20];
#pragma unroll
    for (int o = 0; o < 18; ++o) {
        const float4 wv = sw1[o];
        float a = sb1[o];
        a = fmaf(wv.x, x0, a); a = fmaf(wv.y, x1, a);
        a = fmaf(wv.z, x2, a); a = fmaf(wv.w, x3, a);
        h1[o] = fmaxf(a, 0.0f);
    }
    h1[18] = 0.0f; h1[19] = 0.0f;

    float h2[36];
#pragma unroll
    for (int o = 0; o < 36; ++o) {
        float a = sb2[o];
#pragma unroll
        for (int q = 0; q < 5; ++q) {
            const float4 wv = sw2[o * 5 + q];
            a = fmaf(wv.x, h1[q * 4 + 0], a);
            a = fmaf(wv.y, h1[q * 4 + 1], a);
            a = fmaf(wv.z, h1[q * 4 + 2], a);
            a = fmaf(wv.w, h1[q * 4 + 3], a);
        }
        h2[o] = fmaxf(a, 0.0f);
    }

    float h3[36];
#pragma unroll
    for (int o = 0; o < 36; ++o) {
        float a = sb3[o];
#pragma unroll
        for (int q = 0; q < 9; ++q) {
            const float4 wv = sw3[o * 9 + q];
            a = fmaf(wv.x, h2[q * 4 + 0], a);
            a = fmaf(wv.y, h2[q * 4 + 1], a);
            a = fmaf(wv.z, h2[q * 4 + 2], a);
            a = fmaf(wv.w, h2[q * 4 + 3], a);
        }
        h3[o] = fmaxf(a, 0.0f);
    }

    float v = sb4;
#pragma unroll
    for (int q = 0; q < 9; ++q) {
        const float4 wv = sw4[q];
        v = fmaf(wv.x, h3[q * 4 + 0], v);
        v = fmaf(wv.y, h3[q * 4 + 1], v);
        v = fmaf(wv.z, h3[q * 4 + 2], v);
        v = fmaf(wv.w, h3[q * 4 + 3], v);
    }

    const int2 hw = ((const int2*)tindex)[i];   // (row, col)
    const int pos = atomicAdd(&counts[hw.y], 1);
    if (pos < maxk) {   // never overflows statistically at maxk>=64 (mean 14.2/col)
        uint2 e;
        e.x = __float_as_uint(v);
        e.y = ((unsigned)i << 8) | (unsigned)hw.x;
        list[(size_t)hw.y * maxk + pos] = e;
    }
}

// ---------------------------------------------------------------------------
// Kernel B: block (64,4) = 4 waves, one column per wave. Lane a holds slot a
// (one coalesced 512B load per wave). Dedup via 64-bit per-wave winner table:
// atomicMax(tbl64[row], (key<<32)|value_bits); high word (i<<8|row) orders by
// point index, low word carries the winner's value. After __syncthreads(),
// each lane reads its row's winner VALUE; duplicate reads of the same winner
// are harmless under max. (R4/R5 bug was the init not covering rows 192..199;
// 200 rows / 64 lanes needs 4 strided passes.) Verified correct in R6.
// ---------------------------------------------------------------------------
__global__ void __launch_bounds__(256) colmax_kernel(
    const int* __restrict__ tindex,
    const int* __restrict__ counts,
    const uint2* __restrict__ list,
    float* __restrict__ out,
    int maxk)
{
    __shared__ unsigned long long rowwin[4][200];
    const int lane = threadIdx.x;        // 0..63
    const int y    = threadIdx.y;        // 0..3
    const int w    = blockIdx.x * 4 + y; // column id, always < W_DIM (70400=4*17600)

    const bool empty = (tindex[0] == -1);

    if (blockIdx.x == 0 && lane == 0 && y == 0)
        out[W_DIM] = empty ? 0.0f : 1.0f;    // flag output

    int c = 0;
    if (!empty) {
        c = counts[w];
        if (c > maxk) c = maxk;
    }

    unsigned long long* tbl = rowwin[y];
    tbl[lane]       = 0ull;                  // rows   0.. 63
    tbl[lane + 64]  = 0ull;                  // rows  64..127
    tbl[lane + 128] = 0ull;                  // rows 128..191
    if (lane < 8) tbl[lane + 192] = 0ull;    // rows 192..199
    __syncthreads();

    uint2 e = make_uint2(0u, 0u);
    const bool have = (lane < c);
    if (have) {
        e = list[(size_t)w * maxk + lane];
        // key64: high = (i<<8)|row (orders by i within a row), low = value bits.
        const unsigned long long key64 =
            ((unsigned long long)e.y << 32) | (unsigned long long)e.x;
        atomicMax(&tbl[e.y & 0xFFu], key64);
    }
    __syncthreads();

    float v = FILL_V;
    if (have) {
        const unsigned long long winner = tbl[e.y & 0xFFu];
        v = __uint_as_float((unsigned)(winner & 0xFFFFFFFFull));
    }
#pragma unroll
    for (int off = 32; off > 0; off >>= 1)
        v = fmaxf(v, __shfl_down(v, off, 64));

    if (lane == 0) out[w] = v;
}

extern "C" void kernel_launch(void* const* d_in, const int* in_sizes, int n_in,
                              void* d_out, int out_size, void* d_ws, size_t ws_size,
                              hipStream_t stream) {
    const float* input  = (const float*)d_in[0];
    const int*   tindex = (const int*)d_in[1];   // int32 on device
    const float* w1 = (const float*)d_in[2];
    const float* b1 = (const float*)d_in[3];
    const float* w2 = (const float*)d_in[4];
    const float* b2 = (const float*)d_in[5];
    const float* w3 = (const float*)d_in[6];
    const float* b3 = (const float*)d_in[7];
    const float* w4 = (const float*)d_in[8];
    const float* b4 = (const float*)d_in[9];
    float* out = (float*)d_out;

    // workspace: counts [70400 int] | list [70400][maxk] uint2
    int*   counts = (int*)d_ws;
    uint2* list   = (uint2*)((char*)d_ws + (size_t)W_DIM * sizeof(int));

    size_t avail = (ws_size > (size_t)W_DIM * sizeof(int))
                       ? ws_size - (size_t)W_DIM * sizeof(int) : 0;
    int maxk = (int)(avail / ((size_t)W_DIM * sizeof(uint2)));
    if (maxk > 64) maxk = 64;
    if (maxk < 1)  maxk = 1;

    hipMemsetAsync(counts, 0, (size_t)W_DIM * sizeof(int), stream);

    mlp_scatter_kernel<<<(N_PTS + 255) / 256, 256, 0, stream>>>(
        input, tindex, w1, b1, w2, b2, w3, b3, w4, b4, counts, list, maxk);

    // one wave per column, 4 waves per block; 70400/4 = 17600 exact blocks
    colmax_kernel<<<W_DIM / 4, dim3(64, 4), 0, stream>>>(
        tindex, counts, list, out, maxk);
}

// Round 9
// 192.696 us; speedup vs baseline: 17.5131x; 1.0340x over previous
//
#include <hip/hip_runtime.h>

#define N_PTS 1000000
#define H_DIM 200
#define W_DIM 70400
#define FILL_V -9999999.0f

// ---------------------------------------------------------------------------
// Kernel A: per-point MLP (4->18->36->36->1), ONE point per thread.
// NO LDS: weights are read with wave-uniform indices straight from global --
// the compiler scalarizes these to s_load + v_fmac(v,s,v), so the vector
// memory & LDS pipes carry only the per-point input/index traffic and the
// VALU runs at its 2cyc/FMA floor (~27us for 2.05 GFMA). Layer 4 is FUSED
// into layer 3 (v accumulates as each h3 elem is produced): peak live set is
// h1[18]+h2[36] ~= 56 floats, small enough that the allocator keeps it in
// arch VGPRs (R2..R7: 92-float live set -> 72 arch VGPR + ~150 AGPR spill
// shuffles at 2x VALU cost; 2-pt variant -> scratch, 9 GB HBM, 3.3 ms).
// List entry: .x = value bits, .y = (point_index << 8) | row  (row<200<256).
// Last-write-wins scatter: point survives iff no LATER point hit (row,col).
// ---------------------------------------------------------------------------
__global__ void __launch_bounds__(256) mlp_scatter_kernel(
    const float* __restrict__ input,        // [4][N]
    const int* __restrict__ tindex,         // [N][2] int32 (row, col)
    const float* __restrict__ w1, const float* __restrict__ b1,
    const float* __restrict__ w2, const float* __restrict__ b2,
    const float* __restrict__ w3, const float* __restrict__ b3,
    const float* __restrict__ w4, const float* __restrict__ b4,
    int* __restrict__ counts,               // [W]
    uint2* __restrict__ list,               // [W][maxk]
    int maxk)
{
    // empty-branch (reference: tensor_index[0,0] == -1 -> no scatter)
    if (tindex[0] == -1) return;

    const int i = blockIdx.x * 256 + threadIdx.x;
    if (i >= N_PTS) return;

    const float x0 = input[0 * N_PTS + i];
    const float x1 = input[1 * N_PTS + i];
    const float x2 = input[2 * N_PTS + i];
    const float x3 = input[3 * N_PTS + i];

    float h1[18];
#pragma unroll
    for (int o = 0; o < 18; ++o) {
        float a = b1[o];                       // uniform -> SGPR
        a = fmaf(w1[o * 4 + 0], x0, a);
        a = fmaf(w1[o * 4 + 1], x1, a);
        a = fmaf(w1[o * 4 + 2], x2, a);
        a = fmaf(w1[o * 4 + 3], x3, a);
        h1[o] = fmaxf(a, 0.0f);
    }

    float h2[36];
#pragma unroll
    for (int o = 0; o < 36; ++o) {
        float a = b2[o];
#pragma unroll
        for (int k = 0; k < 18; ++k)
            a = fmaf(w2[o * 18 + k], h1[k], a);
        h2[o] = fmaxf(a, 0.0f);
    }

    // layer 3 with layer 4 fused: never materialize h3[36]
    float v = b4[0];
#pragma unroll
    for (int o = 0; o < 36; ++o) {
        float a = b3[o];
#pragma unroll
        for (int k = 0; k < 36; ++k)
            a = fmaf(w3[o * 36 + k], h2[k], a);
        v = fmaf(w4[o], fmaxf(a, 0.0f), v);
    }

    const int2 hw = ((const int2*)tindex)[i];   // (row, col)
    const int pos = atomicAdd(&counts[hw.y], 1);
    if (pos < maxk) {   // never overflows statistically at maxk>=64 (mean 14.2/col)
        uint2 e;
        e.x = __float_as_uint(v);
        e.y = ((unsigned)i << 8) | (unsigned)hw.x;
        list[(size_t)hw.y * maxk + pos] = e;
    }
}

// ---------------------------------------------------------------------------
// Kernel B: block (64,4) = 4 waves, one column per wave. Lane a holds slot a
// (one coalesced 512B load per wave). Dedup via 64-bit per-wave winner table:
// atomicMax(tbl64[row], (key<<32)|value_bits); high word (i<<8|row) orders by
// point index, low word carries the winner's value. After __syncthreads(),
// each lane reads its row's winner VALUE; duplicate reads of the same winner
// are harmless under max. (R4/R5 bug was the init not covering rows 192..199;
// 200 rows / 64 lanes needs 4 strided passes.) Verified correct in R6/R7.
// ---------------------------------------------------------------------------
__global__ void __launch_bounds__(256) colmax_kernel(
    const int* __restrict__ tindex,
    const int* __restrict__ counts,
    const uint2* __restrict__ list,
    float* __restrict__ out,
    int maxk)
{
    __shared__ unsigned long long rowwin[4][200];
    const int lane = threadIdx.x;        // 0..63
    const int y    = threadIdx.y;        // 0..3
    const int w    = blockIdx.x * 4 + y; // column id, always < W_DIM (70400=4*17600)

    const bool empty = (tindex[0] == -1);

    if (blockIdx.x == 0 && lane == 0 && y == 0)
        out[W_DIM] = empty ? 0.0f : 1.0f;    // flag output

    int c = 0;
    if (!empty) {
        c = counts[w];
        if (c > maxk) c = maxk;
    }

    unsigned long long* tbl = rowwin[y];
    tbl[lane]       = 0ull;                  // rows   0.. 63
    tbl[lane + 64]  = 0ull;                  // rows  64..127
    tbl[lane + 128] = 0ull;                  // rows 128..191
    if (lane < 8) tbl[lane + 192] = 0ull;    // rows 192..199
    __syncthreads();

    uint2 e = make_uint2(0u, 0u);
    const bool have = (lane < c);
    if (have) {
        e = list[(size_t)w * maxk + lane];
        // key64: high = (i<<8)|row (orders by i within a row), low = value bits.
        const unsigned long long key64 =
            ((unsigned long long)e.y << 32) | (unsigned long long)e.x;
        atomicMax(&tbl[e.y & 0xFFu], key64);
    }
    __syncthreads();

    float v = FILL_V;
    if (have) {
        const unsigned long long winner = tbl[e.y & 0xFFu];
        v = __uint_as_float((unsigned)(winner & 0xFFFFFFFFull));
    }
#pragma unroll
    for (int off = 32; off > 0; off >>= 1)
        v = fmaxf(v, __shfl_down(v, off, 64));

    if (lane == 0) out[w] = v;
}

extern "C" void kernel_launch(void* const* d_in, const int* in_sizes, int n_in,
                              void* d_out, int out_size, void* d_ws, size_t ws_size,
                              hipStream_t stream) {
    const float* input  = (const float*)d_in[0];
    const int*   tindex = (const int*)d_in[1];   // int32 on device
    const float* w1 = (const float*)d_in[2];
    const float* b1 = (const float*)d_in[3];
    const float* w2 = (const float*)d_in[4];
    const float* b2 = (const float*)d_in[5];
    const float* w3 = (const float*)d_in[6];
    const float* b3 = (const float*)d_in[7];
    const float* w4 = (const float*)d_in[8];
    const float* b4 = (const float*)d_in[9];
    float* out = (float*)d_out;

    // workspace: counts [70400 int] | list [70400][maxk] uint2
    int*   counts = (int*)d_ws;
    uint2* list   = (uint2*)((char*)d_ws + (size_t)W_DIM * sizeof(int));

    size_t avail = (ws_size > (size_t)W_DIM * sizeof(int))
                       ? ws_size - (size_t)W_DIM * sizeof(int) : 0;
    int maxk = (int)(avail / ((size_t)W_DIM * sizeof(uint2)));
    if (maxk > 64) maxk = 64;
    if (maxk < 1)  maxk = 1;

    hipMemsetAsync(counts, 0, (size_t)W_DIM * sizeof(int), stream);

    mlp_scatter_kernel<<<(N_PTS + 255) / 256, 256, 0, stream>>>(
        input, tindex, w1, b1, w2, b2, w3, b3, w4, b4, counts, list, maxk);

    // one wave per column, 4 waves per block; 70400/4 = 17600 exact blocks
    colmax_kernel<<<W_DIM / 4, dim3(64, 4), 0, stream>>>(
        tindex, counts, list, out, maxk);
}

// Round 10
// 173.618 us; speedup vs baseline: 19.4375x; 1.1099x over previous
//
#include <hip/hip_runtime.h>

#define N_PTS 1000000
#define H_DIM 200
#define W_DIM 70400
#define FILL_V -9999999.0f

typedef float v2f __attribute__((ext_vector_type(2)));

__device__ __forceinline__ v2f fma2(v2f a, v2f b, v2f c) {
    return __builtin_elementwise_fma(a, b, c);   // -> v_pk_fma_f32 on gfx950
}

// ---------------------------------------------------------------------------
// Kernel A: per-point MLP (4->18->36->36->1), ONE point per thread.
// Weights read wave-uniform from global (scalarized to s_load by compiler;
// R9 counters: LDS=0, SGPR=112, no scratch). Dot products PACKED over k as
// float2 -> v_pk_fma_f32 (2 FMA/instr): issue ~1310 VALU/point vs 2052
// scalar. Layer 4 fused into layer 3 (h3 never materialized): live set
// h1(9 v2f)+h2(18 v2f) ~= 56 floats -> stays in arch VGPRs.
// History: LDS-staged weights = 117us (51% VALU, AGPR shuffle); scalar
// weights 1-pt = 104us; 2-pt variant = scratch spill, 9 GB HBM, 3.3 ms.
// List entry: .x = value bits, .y = (point_index << 8) | row  (row<200<256).
// Last-write-wins scatter: point survives iff no LATER point hit (row,col).
// ---------------------------------------------------------------------------
__global__ void __launch_bounds__(256) mlp_scatter_kernel(
    const float* __restrict__ input,        // [4][N]
    const int* __restrict__ tindex,         // [N][2] int32 (row, col)
    const float* __restrict__ w1, const float* __restrict__ b1,
    const float* __restrict__ w2, const float* __restrict__ b2,
    const float* __restrict__ w3, const float* __restrict__ b3,
    const float* __restrict__ w4, const float* __restrict__ b4,
    int* __restrict__ counts,               // [W]
    uint2* __restrict__ list,               // [W][maxk]
    int maxk)
{
    // empty-branch (reference: tensor_index[0,0] == -1 -> no scatter)
    if (tindex[0] == -1) return;

    const int i = blockIdx.x * 256 + threadIdx.x;
    if (i >= N_PTS) return;

    const v2f* __restrict__ w1v = (const v2f*)w1;   // rows of 4 = 2 v2f
    const v2f* __restrict__ w2v = (const v2f*)w2;   // rows of 18 = 9 v2f
    const v2f* __restrict__ w3v = (const v2f*)w3;   // rows of 36 = 18 v2f

    const v2f x01 = { input[0 * N_PTS + i], input[1 * N_PTS + i] };
    const v2f x23 = { input[2 * N_PTS + i], input[3 * N_PTS + i] };

    // layer 1: 18 outputs, k packed (4 -> 2 pairs)
    v2f h1v[9];
#pragma unroll
    for (int o = 0; o < 18; ++o) {
        v2f acc = { b1[o], 0.0f };               // bias rides in .x
        acc = fma2(w1v[o * 2 + 0], x01, acc);
        acc = fma2(w1v[o * 2 + 1], x23, acc);
        const float h = fmaxf(acc.x + acc.y, 0.0f);
        if (o & 1) h1v[o >> 1].y = h; else h1v[o >> 1].x = h;
    }

    // layer 2: 36 outputs, k packed (18 -> 9 pairs)
    v2f h2v[18];
#pragma unroll
    for (int o = 0; o < 36; ++o) {
        v2f acc = { b2[o], 0.0f };
#pragma unroll
        for (int q = 0; q < 9; ++q)
            acc = fma2(w2v[o * 9 + q], h1v[q], acc);
        const float h = fmaxf(acc.x + acc.y, 0.0f);
        if (o & 1) h2v[o >> 1].y = h; else h2v[o >> 1].x = h;
    }

    // layer 3 (k packed, 36 -> 18 pairs) with layer 4 fused
    float v = b4[0];
#pragma unroll
    for (int o = 0; o < 36; ++o) {
        v2f acc = { b3[o], 0.0f };
#pragma unroll
        for (int q = 0; q < 18; ++q)
            acc = fma2(w3v[o * 18 + q], h2v[q], acc);
        v = fmaf(w4[o], fmaxf(acc.x + acc.y, 0.0f), v);
    }

    const int2 hw = ((const int2*)tindex)[i];   // (row, col)
    const int pos = atomicAdd(&counts[hw.y], 1);
    if (pos < maxk) {   // never overflows statistically at maxk>=64 (mean 14.2/col)
        uint2 e;
        e.x = __float_as_uint(v);
        e.y = ((unsigned)i << 8) | (unsigned)hw.x;
        list[(size_t)hw.y * maxk + pos] = e;
    }
}

// ---------------------------------------------------------------------------
// Kernel B: block (64,4) = 4 waves, one column per wave. Lane a holds slot a
// (one coalesced load per wave). Dedup via 64-bit per-wave winner table:
// atomicMax(tbl64[row], (key<<32)|value_bits); high word (i<<8|row) orders by
// point index, low word carries the winner's value. After __syncthreads(),
// each lane reads its row's winner VALUE; duplicate reads of the same winner
// are harmless under max. (R4/R5 bug: init must cover all 200 rows -- 64
// lanes need 4 strided passes.) Verified correct R6-R9.
// ---------------------------------------------------------------------------
__global__ void __launch_bounds__(256) colmax_kernel(
    const int* __restrict__ tindex,
    const int* __restrict__ counts,
    const uint2* __restrict__ list,
    float* __restrict__ out,
    int maxk)
{
    __shared__ unsigned long long rowwin[4][200];
    const int lane = threadIdx.x;        // 0..63
    const int y    = threadIdx.y;        // 0..3
    const int w    = blockIdx.x * 4 + y; // column id, always < W_DIM (70400=4*17600)

    const bool empty = (tindex[0] == -1);

    if (blockIdx.x == 0 && lane == 0 && y == 0)
        out[W_DIM] = empty ? 0.0f : 1.0f;    // flag output

    int c = 0;
    if (!empty) {
        c = counts[w];
        if (c > maxk) c = maxk;
    }

    unsigned long long* tbl = rowwin[y];
    tbl[lane]       = 0ull;                  // rows   0.. 63
    tbl[lane + 64]  = 0ull;                  // rows  64..127
    tbl[lane + 128] = 0ull;                  // rows 128..191
    if (lane < 8) tbl[lane + 192] = 0ull;    // rows 192..199
    __syncthreads();

    uint2 e = make_uint2(0u, 0u);
    const bool have = (lane < c);
    if (have) {
        e = list[(size_t)w * maxk + lane];
        const unsigned long long key64 =
            ((unsigned long long)e.y << 32) | (unsigned long long)e.x;
        atomicMax(&tbl[e.y & 0xFFu], key64);
    }
    __syncthreads();

    float v = FILL_V;
    if (have) {
        const unsigned long long winner = tbl[e.y & 0xFFu];
        v = __uint_as_float((unsigned)(winner & 0xFFFFFFFFull));
    }
#pragma unroll
    for (int off = 32; off > 0; off >>= 1)
        v = fmaxf(v, __shfl_down(v, off, 64));

    if (lane == 0) out[w] = v;
}

extern "C" void kernel_launch(void* const* d_in, const int* in_sizes, int n_in,
                              void* d_out, int out_size, void* d_ws, size_t ws_size,
                              hipStream_t stream) {
    const float* input  = (const float*)d_in[0];
    const int*   tindex = (const int*)d_in[1];   // int32 on device
    const float* w1 = (const float*)d_in[2];
    const float* b1 = (const float*)d_in[3];
    const float* w2 = (const float*)d_in[4];
    const float* b2 = (const float*)d_in[5];
    const float* w3 = (const float*)d_in[6];
    const float* b3 = (const float*)d_in[7];
    const float* w4 = (const float*)d_in[8];
    const float* b4 = (const float*)d_in[9];
    float* out = (float*)d_out;

    // workspace: counts [70400 int] | list [70400][maxk] uint2
    int*   counts = (int*)d_ws;
    uint2* list   = (uint2*)((char*)d_ws + (size_t)W_DIM * sizeof(int));

    size_t avail = (ws_size > (size_t)W_DIM * sizeof(int))
                       ? ws_size - (size_t)W_DIM * sizeof(int) : 0;
    int maxk = (int)(avail / ((size_t)W_DIM * sizeof(uint2)));
    if (maxk > 64) maxk = 64;
    if (maxk < 1)  maxk = 1;

    hipMemsetAsync(counts, 0, (size_t)W_DIM * sizeof(int), stream);

    mlp_scatter_kernel<<<(N_PTS + 255) / 256, 256, 0, stream>>>(
        input, tindex, w1, b1, w2, b2, w3, b3, w4, b4, counts, list, maxk);

    // one wave per column, 4 waves per block; 70400/4 = 17600 exact blocks
    colmax_kernel<<<W_DIM / 4, dim3(64, 4), 0, stream>>>(
        tindex, counts, list, out, maxk);
}